// Round 9
// baseline (391.733 us; speedup 1.0000x reference)
//
#include <hip/hip_runtime.h>
#include <hip/hip_bf16.h>
#include <stdint.h>

#define NPTS 8192
#define MSTRIDE 260   // LDS mask row stride in dwords (16B-aligned, conflict-free)

typedef float f32x4 __attribute__((ext_vector_type(4)));
typedef short s16x8 __attribute__((ext_vector_type(8)));

// bf16 round-to-nearest-even
__device__ __forceinline__ unsigned short f2bf(float f) {
    unsigned int u = __builtin_bit_cast(unsigned int, f);
    u += 0x7FFFu + ((u >> 16) & 1u);
    return (unsigned short)(u >> 16);
}

// Y in exact MFMA-B-fragment order (16x16x32 bf16):
// frag (kb, ct, lane L=quad*16+n): 8 elems k=kb*32+quad*8+t, col=ct*16+n,
// flat uint4 index = (kb*4 + ct)*64 + L. A wave's (kb,ct) read = contiguous 1KB.

// ---------- kernel 1: mask bits (LDS) -> maskb dump + float expand + dinv + Y1 ----------
// grid 512 x 256; block owns 16 rows.
// Phase A: ballot loop, bits to LDS only (no global stores in hot loop).
// Phase B: bits -> f32x4 nontemporal stores (1 KB/wave-inst, 4x fewer store insts).
__global__ __launch_bounds__(256) void k_mask(const float* __restrict__ states,
                                              const float* __restrict__ W1,
                                              float* __restrict__ mout,
                                              unsigned long long* __restrict__ maskb,
                                              float* __restrict__ dinv,
                                              uint4* __restrict__ y1) {
    __shared__ float xs[NPTS];                    // 32 KB
    __shared__ float ys[NPTS];                    // 32 KB
    __shared__ unsigned long long mbits[16 * 128];// 16 KB = 1024 uint4
    __shared__ float dls[16];
    int tid = threadIdx.x;
    for (int r = tid; r < NPTS; r += 256) {
        float4 s = ((const float4*)states)[r];
        xs[r] = s.x; ys[r] = s.y;
    }
    __syncthreads();
    int wv = tid >> 6, L = tid & 63;
    int rowbase = blockIdx.x * 16 + wv * 4;
    // ---- phase A: distance ballots -> LDS bits + degree ----
#pragma unroll
    for (int rr = 0; rr < 4; ++rr) {
        int row = wv * 4 + rr;
        float xi = xs[rowbase + rr], yi = ys[rowbase + rr];
        int deg = 0;
        for (int it = 0; it < 128; ++it) {
            int j = it * 64 + L;
            float dx = xi - xs[j];
            float dy = yi - ys[j];
            // must match numpy fp32 (dx*dx)+(dy*dy), no FMA contraction:
            float d2 = __fadd_rn(__fmul_rn(dx, dx), __fmul_rn(dy, dy));
            bool pred = (d2 <= 1.0f);
            unsigned long long b = __ballot(pred);
            if (L == 0) mbits[row * 128 + it] = b;
            deg += (int)__popcll(b);
        }
        if (L == 0) {
            float dv = rsqrtf((float)deg);
            dinv[rowbase + rr] = dv;
            dls[row] = dv;
        }
    }
    __syncthreads();
    // ---- coalesced maskb dump: 16 KB = 1024 uint4 per block ----
    {
        const uint4* s = (const uint4*)mbits;
        uint4* d = (uint4*)(maskb + (size_t)blockIdx.x * 16 * 128);
        for (int e = tid; e < 1024; e += 256) d[e] = s[e];
    }
    // ---- phase B: bits -> mask floats, f32x4 NT stores ----
#pragma unroll
    for (int rr = 0; rr < 4; ++rr) {
        int row = wv * 4 + rr;
        const unsigned long long* mr = mbits + row * 128;
        float* orow = mout + (size_t)(rowbase + rr) * NPTS;
        int wsel = L >> 4, bsel = (L & 15) * 4;
        for (int it2 = 0; it2 < 32; ++it2) {
            unsigned long long word = mr[it2 * 4 + wsel];
            unsigned int nib = (unsigned int)(word >> bsel) & 0xFu;
            f32x4 v;
            v.x = (float)(nib & 1u);
            v.y = (float)((nib >> 1) & 1u);
            v.z = (float)((nib >> 2) & 1u);
            v.w = (float)((nib >> 3) & 1u);
            __builtin_nontemporal_store(v, (f32x4*)(orow + it2 * 256 + L * 4));
        }
    }
    // ---- Y1: 128 threads produce this block's 128 uint4 fragments ----
    if (tid < 128) {
        int ql = tid >> 6;            // local quad 0/1
        int ct = (tid >> 4) & 3;
        int nn = tid & 15;
        int col = ct * 16 + nn;
        float w0 = W1[col], w1 = W1[64 + col], w2 = W1[128 + col], w3 = W1[192 + col];
        unsigned short frag[8];
#pragma unroll
        for (int t = 0; t < 8; ++t) {
            int rloc = ql * 8 + t;
            int k = blockIdx.x * 16 + rloc;
            float4 s = ((const float4*)states)[k];
            float acc = s.x * w0 + s.y * w1 + s.z * w2 + s.w * w3;
            frag[t] = f2bf(dls[rloc] * acc);
        }
        uint4 u;
        u.x = (unsigned)frag[0] | ((unsigned)frag[1] << 16);
        u.y = (unsigned)frag[2] | ((unsigned)frag[3] << 16);
        u.z = (unsigned)frag[4] | ((unsigned)frag[5] << 16);
        u.w = (unsigned)frag[6] | ((unsigned)frag[7] << 16);
        int kb = blockIdx.x >> 1;
        int quad = ql + 2 * (blockIdx.x & 1);
        y1[(kb * 4 + ct) * 64 + quad * 16 + nn] = u;
    }
}

// ---------- shared agg core: full-K aggregation for 32 rows + reduce + relu ----------
// 512 threads, 8 waves; wave w covers K-chunk [w*1024,(w+1)*1024).
// Mask rows staged in LDS; depth-3 rotating register prefetch of B fragments.
__device__ __forceinline__ void agg_core(const uint4* __restrict__ y,
                                         const unsigned int* __restrict__ maskb,
                                         const float* __restrict__ dinv,
                                         const float* __restrict__ bias,
                                         float* __restrict__ redbuf,        // [8*2048]
                                         unsigned int* __restrict__ mlds,   // [32*MSTRIDE]
                                         float* __restrict__ hbuf,          // [32*66]
                                         int R0) {
    int tid = threadIdx.x;
    // ---- stage 32 mask rows (32 KB) into LDS with coalesced dwordx4 ----
    {
        const uint4* src = (const uint4*)(maskb + (size_t)R0 * 256);
        for (int e = tid; e < 2048; e += 512) {
            uint4 v = src[e];
            int r = e >> 6, c4 = e & 63;
            *(uint4*)(mlds + r * MSTRIDE + c4 * 4) = v;
        }
    }
    __syncthreads();
    int w = tid >> 6, L = tid & 63;
    int n = L & 15, quad = L >> 4;
    const unsigned int* mr0 = mlds + n * MSTRIDE + w * 32;
    const unsigned int* mr1 = mr0 + 16 * MSTRIDE;
    const uint4* yb = y + (size_t)w * 8192 + L;

    f32x4 acc[2][4] = {{{0,0,0,0},{0,0,0,0},{0,0,0,0},{0,0,0,0}},
                       {{0,0,0,0},{0,0,0,0},{0,0,0,0},{0,0,0,0}}};
    uint4 B[3][4];
#pragma unroll
    for (int s = 0; s < 3; ++s)
#pragma unroll
        for (int ct = 0; ct < 4; ++ct) B[s][ct] = yb[s * 256 + ct * 64];
    unsigned int mw0 = mr0[0], mw1 = mr1[0];

#pragma unroll
    for (int kk = 0; kk < 32; ++kk) {
        int cur = kk % 3;
        unsigned int mwn0 = 0, mwn1 = 0;
        if (kk + 1 < 32) { mwn0 = mr0[kk + 1]; mwn1 = mr1[kk + 1]; }
        unsigned int by0 = (mw0 >> (quad * 8)) & 0xFFu;
        unsigned int by1 = (mw1 >> (quad * 8)) & 0xFFu;
        s16x8 a0, a1;
#pragma unroll
        for (int t = 0; t < 8; ++t) {
            a0[t] = (short)(((by0 >> t) & 1u) ? 0x3F80 : 0);
            a1[t] = (short)(((by1 >> t) & 1u) ? 0x3F80 : 0);
        }
#pragma unroll
        for (int ct = 0; ct < 4; ++ct) {
            s16x8 b = __builtin_bit_cast(s16x8, B[cur][ct]);
            acc[0][ct] = __builtin_amdgcn_mfma_f32_16x16x32_bf16(a0, b, acc[0][ct], 0, 0, 0);
            acc[1][ct] = __builtin_amdgcn_mfma_f32_16x16x32_bf16(a1, b, acc[1][ct], 0, 0, 0);
        }
        if (kk + 3 < 32) {
            const uint4* p = yb + (kk + 3) * 256;
#pragma unroll
            for (int ct = 0; ct < 4; ++ct) B[cur][ct] = p[ct * 64];
        }
        mw0 = mwn0; mw1 = mwn1;
    }
    // dump partials: D layout col = lane&15, row = quad*4 + reg
    float* rb = redbuf + w * 2048;
#pragma unroll
    for (int g = 0; g < 2; ++g)
#pragma unroll
        for (int ct = 0; ct < 4; ++ct)
#pragma unroll
            for (int r = 0; r < 4; ++r)
                rb[(g * 16 + quad * 4 + r) * 64 + ct * 16 + n] = acc[g][ct][r];
    __syncthreads();
    // reduce 8 partials + bias + relu -> hbuf
    for (int e = tid; e < 2048; e += 512) {
        float z = 0.0f;
#pragma unroll
        for (int ww = 0; ww < 8; ++ww) z += redbuf[ww * 2048 + e];
        int row = e >> 6, col = e & 63;
        hbuf[row * 66 + col] = fmaxf(dinv[R0 + row] * z + bias[col], 0.0f);
    }
    __syncthreads();
}

// ---------- kernel 2: layer 1 agg + h1 + Y2 fragments (fused) ----------
__global__ __launch_bounds__(512) void k_layer1(const uint4* __restrict__ y1,
                                                const unsigned int* __restrict__ maskb,
                                                const float* __restrict__ dinv,
                                                const float* __restrict__ b1,
                                                const float* __restrict__ W2,
                                                uint4* __restrict__ y2) {
    __shared__ float redbuf[8 * 2048];             // 64 KB
    __shared__ unsigned int mlds[32 * MSTRIDE];    // 32.5 KB
    __shared__ float hbuf[32 * 66];                // 8.25 KB
    __shared__ float w2s[4096];                    // 16 KB
    int tid = threadIdx.x;
    for (int s = tid; s < 4096; s += 512) w2s[s] = W2[s];
    int R0 = blockIdx.x * 32;
    agg_core(y1, maskb, dinv, b1, redbuf, mlds, hbuf, R0);
    // y2 = dinv * (h1 @ W2), written straight into fragment order (all 512 thr).
    {
        int nn = tid & 15, q = (tid >> 4) & 3, ct = (tid >> 6) & 3, half = tid >> 8;
        int col = ct * 16 + nn;
        float dot[4] = {0, 0, 0, 0};
        for (int m = 0; m < 64; ++m) {
            float wv = w2s[m * 64 + col];
#pragma unroll
            for (int t = 0; t < 4; ++t)
                dot[t] = fmaf(hbuf[(q * 8 + half * 4 + t) * 66 + m], wv, dot[t]);
        }
        unsigned short v[4];
#pragma unroll
        for (int t = 0; t < 4; ++t) v[t] = f2bf(dinv[R0 + q * 8 + half * 4 + t] * dot[t]);
        uint2 u;
        u.x = (unsigned)v[0] | ((unsigned)v[1] << 16);
        u.y = (unsigned)v[2] | ((unsigned)v[3] << 16);
        int fragidx = (blockIdx.x * 4 + ct) * 64 + q * 16 + nn;
        ((uint2*)y2)[fragidx * 2 + half] = u;
    }
}

// ---------- kernel 3: layer 2 agg + h2 + scalar head (fused) ----------
__global__ __launch_bounds__(512) void k_layer2(const uint4* __restrict__ y2,
                                                const unsigned int* __restrict__ maskb,
                                                const float* __restrict__ dinv,
                                                const float* __restrict__ b2,
                                                const float* __restrict__ cw,
                                                const float* __restrict__ cb,
                                                float* __restrict__ out) {
    __shared__ float redbuf[8 * 2048];             // 64 KB
    __shared__ unsigned int mlds[32 * MSTRIDE];    // 32.5 KB
    __shared__ float hbuf[32 * 66];                // 8.25 KB
    __shared__ float cws[64];
    int tid = threadIdx.x;
    if (tid < 64) cws[tid] = cw[tid];
    int R0 = blockIdx.x * 32;
    agg_core(y2, maskb, dinv, b2, redbuf, mlds, hbuf, R0);
    // out[i] = h2[i,:] . cw + cb ; 512 threads = 32 rows x 16 groups of 4 cols
    int row = tid >> 4, cg = tid & 15;
    float v = 0.0f;
#pragma unroll
    for (int e = 0; e < 4; ++e) {
        int c = cg * 4 + e;
        v = fmaf(hbuf[row * 66 + c], cws[c], v);
    }
    v += __shfl_down(v, 8);
    v += __shfl_down(v, 4);
    v += __shfl_down(v, 2);
    v += __shfl_down(v, 1);
    if (cg == 0) out[R0 + row] = v + cb[0];
}

// ---------- launch ----------
extern "C" void kernel_launch(void* const* d_in, const int* in_sizes, int n_in,
                              void* d_out, int out_size, void* d_ws, size_t ws_size,
                              hipStream_t stream) {
    const float* states = (const float*)d_in[0];
    const float* W1 = (const float*)d_in[1];
    const float* b1 = (const float*)d_in[2];
    const float* W2 = (const float*)d_in[3];
    const float* b2 = (const float*)d_in[4];
    const float* cw = (const float*)d_in[5];
    const float* cb = (const float*)d_in[6];
    float* out = (float*)d_out;
    float* mout = out + NPTS;  // mask floats follow out[8192]

    char* ws = (char*)d_ws;
    float* dinv               = (float*)(ws);                          // 64 KB
    unsigned long long* maskb = (unsigned long long*)(ws + (1 << 16)); // 8 MiB
    uint4* y1                 = (uint4*)(ws + (1 << 16) + (8 << 20));  // 1 MiB
    uint4* y2                 = (uint4*)(ws + (1 << 16) + (9 << 20));  // 1 MiB

    hipLaunchKernelGGL(k_mask,   dim3(512), dim3(256), 0, stream,
                       states, W1, mout, maskb, dinv, y1);
    hipLaunchKernelGGL(k_layer1, dim3(256), dim3(512), 0, stream,
                       y1, (const unsigned int*)maskb, dinv, b1, W2, y2);
    hipLaunchKernelGGL(k_layer2, dim3(256), dim3(512), 0, stream,
                       y2, (const unsigned int*)maskb, dinv, b2, cw, cb, out);
}

// Round 11
// 335.022 us; speedup vs baseline: 1.1693x; 1.1693x over previous
//
#include <hip/hip_runtime.h>
#include <hip/hip_bf16.h>
#include <stdint.h>

#define NPTS 8192
#define MSTRIDE 260   // LDS mask row stride in dwords (16B-aligned, conflict-free)

typedef float f32x4 __attribute__((ext_vector_type(4)));
typedef short s16x8 __attribute__((ext_vector_type(8)));

// bf16 round-to-nearest-even
__device__ __forceinline__ unsigned short f2bf(float f) {
    unsigned int u = __builtin_bit_cast(unsigned int, f);
    u += 0x7FFFu + ((u >> 16) & 1u);
    return (unsigned short)(u >> 16);
}

// Y in exact MFMA-B-fragment order (16x16x32 bf16):
// frag (kb, ct, lane L=quad*16+n): 8 elems k=kb*32+quad*8+t, col=ct*16+n,
// flat uint4 index = (kb*4 + ct)*64 + L. A wave's (kb,ct) read = contiguous 1KB.

// ---------- kernel 1: mask floats + packed bits + dinv + Y1 (fused) ----------
// grid 512 x 256; block owns 16 rows. SoA LDS (conflict-free), it-outer loop
// (xj loaded once per chunk, reused by 4 rows). Stores stay INTERLEAVED with
// compute (write drain overlaps VALU — phase-splitting this regressed +57us, R9).
__global__ __launch_bounds__(256) void k_mask(const float* __restrict__ states,
                                              const float* __restrict__ W1,
                                              float* __restrict__ mout,
                                              unsigned long long* __restrict__ maskb,
                                              float* __restrict__ dinv,
                                              uint4* __restrict__ y1) {
    __shared__ float xs[NPTS];  // 32 KB
    __shared__ float ys[NPTS];  // 32 KB
    __shared__ float dls[16];
    int tid = threadIdx.x;
    for (int r = tid; r < NPTS; r += 256) {
        float4 s = ((const float4*)states)[r];
        xs[r] = s.x; ys[r] = s.y;
    }
    __syncthreads();
    int wv = tid >> 6, L = tid & 63;
    int rowbase = blockIdx.x * 16 + wv * 4;
    float xi[4], yi[4];
    int deg[4] = {0, 0, 0, 0};
#pragma unroll
    for (int rr = 0; rr < 4; ++rr) { xi[rr] = xs[rowbase + rr]; yi[rr] = ys[rowbase + rr]; }
    for (int it = 0; it < 128; ++it) {
        int j = it * 64 + L;
        float xj = xs[j], yj = ys[j];
#pragma unroll
        for (int rr = 0; rr < 4; ++rr) {
            float dx = xi[rr] - xj;
            float dy = yi[rr] - yj;
            // must match numpy fp32 (dx*dx)+(dy*dy), no FMA contraction:
            float d2 = __fadd_rn(__fmul_rn(dx, dx), __fmul_rn(dy, dy));
            bool pred = (d2 <= 1.0f);
            __builtin_nontemporal_store(pred ? 1.0f : 0.0f,
                                        &mout[(size_t)(rowbase + rr) * NPTS + j]);
            unsigned long long b = __ballot(pred);
            if (L == 0) maskb[(size_t)(rowbase + rr) * 128 + it] = b;
            deg[rr] += (int)__popcll(b);
        }
    }
    if (L == 0) {
#pragma unroll
        for (int rr = 0; rr < 4; ++rr) {
            float dv = rsqrtf((float)deg[rr]);
            dinv[rowbase + rr] = dv;
            dls[wv * 4 + rr] = dv;
        }
    }
    __syncthreads();
    // Y1: 128 threads produce this block's 128 uint4 fragments
    if (tid < 128) {
        int ql = tid >> 6;            // local quad 0/1
        int ct = (tid >> 4) & 3;
        int nn = tid & 15;
        int col = ct * 16 + nn;
        float w0 = W1[col], w1 = W1[64 + col], w2 = W1[128 + col], w3 = W1[192 + col];
        unsigned short frag[8];
#pragma unroll
        for (int t = 0; t < 8; ++t) {
            int rloc = ql * 8 + t;
            int k = blockIdx.x * 16 + rloc;
            float4 s = ((const float4*)states)[k];
            float acc = s.x * w0 + s.y * w1 + s.z * w2 + s.w * w3;
            frag[t] = f2bf(dls[rloc] * acc);
        }
        uint4 u;
        u.x = (unsigned)frag[0] | ((unsigned)frag[1] << 16);
        u.y = (unsigned)frag[2] | ((unsigned)frag[3] << 16);
        u.z = (unsigned)frag[4] | ((unsigned)frag[5] << 16);
        u.w = (unsigned)frag[6] | ((unsigned)frag[7] << 16);
        int kb = blockIdx.x >> 1;
        int quad = ql + 2 * (blockIdx.x & 1);
        y1[(kb * 4 + ct) * 64 + quad * 16 + nn] = u;
    }
}

// ---------- shared agg core: full-K aggregation for 32 rows + reduce + relu ----------
// 512 threads, 8 waves; wave w covers K-chunk [w*1024,(w+1)*1024).
// Mask rows staged in LDS; depth-2 rotating register prefetch of B fragments.
__device__ __forceinline__ void agg_core(const uint4* __restrict__ y,
                                         const unsigned int* __restrict__ maskb,
                                         const float* __restrict__ dinv,
                                         const float* __restrict__ bias,
                                         float* __restrict__ redbuf,        // [8*2048]
                                         unsigned int* __restrict__ mlds,   // [32*MSTRIDE]
                                         float* __restrict__ hbuf,          // [32*66]
                                         int R0) {
    int tid = threadIdx.x;
    // ---- stage 32 mask rows (32 KB) into LDS with coalesced dwordx4 ----
    {
        const uint4* src = (const uint4*)(maskb + (size_t)R0 * 256);
        for (int e = tid; e < 2048; e += 512) {
            uint4 v = src[e];
            int r = e >> 6, c4 = e & 63;
            *(uint4*)(mlds + r * MSTRIDE + c4 * 4) = v;
        }
    }
    __syncthreads();
    int w = tid >> 6, L = tid & 63;
    int n = L & 15, quad = L >> 4;
    const unsigned int* mr0 = mlds + n * MSTRIDE + w * 32;
    const unsigned int* mr1 = mr0 + 16 * MSTRIDE;
    const uint4* yb = y + (size_t)w * 8192 + L;

    f32x4 acc[2][4] = {{{0,0,0,0},{0,0,0,0},{0,0,0,0},{0,0,0,0}},
                       {{0,0,0,0},{0,0,0,0},{0,0,0,0},{0,0,0,0}}};
    uint4 b0[4], b1[4];
#pragma unroll
    for (int ct = 0; ct < 4; ++ct) b0[ct] = yb[ct * 64];
#pragma unroll
    for (int ct = 0; ct < 4; ++ct) b1[ct] = yb[256 + ct * 64];

    for (int kk = 0; kk < 32; kk += 2) {
        uint4 bn[4];
        // even step: compute with b0, prefetch kk+2
        if (kk + 2 < 32) {
            const uint4* p = yb + (kk + 2) * 256;
#pragma unroll
            for (int ct = 0; ct < 4; ++ct) bn[ct] = p[ct * 64];
        }
        {
            unsigned int mw0 = mr0[kk], mw1 = mr1[kk];
            unsigned int by0 = (mw0 >> (quad * 8)) & 0xFFu;
            unsigned int by1 = (mw1 >> (quad * 8)) & 0xFFu;
            s16x8 a0, a1;
#pragma unroll
            for (int t = 0; t < 8; ++t) {
                a0[t] = (short)(((by0 >> t) & 1u) ? 0x3F80 : 0);
                a1[t] = (short)(((by1 >> t) & 1u) ? 0x3F80 : 0);
            }
#pragma unroll
            for (int ct = 0; ct < 4; ++ct) {
                s16x8 b = __builtin_bit_cast(s16x8, b0[ct]);
                acc[0][ct] = __builtin_amdgcn_mfma_f32_16x16x32_bf16(a0, b, acc[0][ct], 0, 0, 0);
                acc[1][ct] = __builtin_amdgcn_mfma_f32_16x16x32_bf16(a1, b, acc[1][ct], 0, 0, 0);
            }
        }
#pragma unroll
        for (int ct = 0; ct < 4; ++ct) b0[ct] = bn[ct];
        // odd step: compute with b1, prefetch kk+3
        if (kk + 3 < 32) {
            const uint4* p = yb + (kk + 3) * 256;
#pragma unroll
            for (int ct = 0; ct < 4; ++ct) bn[ct] = p[ct * 64];
        }
        {
            unsigned int mw0 = mr0[kk + 1], mw1 = mr1[kk + 1];
            unsigned int by0 = (mw0 >> (quad * 8)) & 0xFFu;
            unsigned int by1 = (mw1 >> (quad * 8)) & 0xFFu;
            s16x8 a0, a1;
#pragma unroll
            for (int t = 0; t < 8; ++t) {
                a0[t] = (short)(((by0 >> t) & 1u) ? 0x3F80 : 0);
                a1[t] = (short)(((by1 >> t) & 1u) ? 0x3F80 : 0);
            }
#pragma unroll
            for (int ct = 0; ct < 4; ++ct) {
                s16x8 b = __builtin_bit_cast(s16x8, b1[ct]);
                acc[0][ct] = __builtin_amdgcn_mfma_f32_16x16x32_bf16(a0, b, acc[0][ct], 0, 0, 0);
                acc[1][ct] = __builtin_amdgcn_mfma_f32_16x16x32_bf16(a1, b, acc[1][ct], 0, 0, 0);
            }
        }
#pragma unroll
        for (int ct = 0; ct < 4; ++ct) b1[ct] = bn[ct];
    }
    // dump partials: D layout col = lane&15, row = quad*4 + reg
    float* rb = redbuf + w * 2048;
#pragma unroll
    for (int g = 0; g < 2; ++g)
#pragma unroll
        for (int ct = 0; ct < 4; ++ct)
#pragma unroll
            for (int r = 0; r < 4; ++r)
                rb[(g * 16 + quad * 4 + r) * 64 + ct * 16 + n] = acc[g][ct][r];
    __syncthreads();
    // reduce 8 partials + bias + relu -> hbuf
    for (int e = tid; e < 2048; e += 512) {
        float z = 0.0f;
#pragma unroll
        for (int ww = 0; ww < 8; ++ww) z += redbuf[ww * 2048 + e];
        int row = e >> 6, col = e & 63;
        hbuf[row * 66 + col] = fmaxf(dinv[R0 + row] * z + bias[col], 0.0f);
    }
    __syncthreads();
}

// ---------- kernel 2: layer 1 agg + h1 + Y2 fragments (fused) ----------
__global__ __launch_bounds__(512) void k_layer1(const uint4* __restrict__ y1,
                                                const unsigned int* __restrict__ maskb,
                                                const float* __restrict__ dinv,
                                                const float* __restrict__ b1,
                                                const float* __restrict__ W2,
                                                uint4* __restrict__ y2) {
    __shared__ float redbuf[8 * 2048];             // 64 KB
    __shared__ unsigned int mlds[32 * MSTRIDE];    // 32.5 KB
    __shared__ float hbuf[32 * 66];                // 8.25 KB
    __shared__ float w2s[4096];                    // 16 KB
    int tid = threadIdx.x;
    for (int s = tid; s < 4096; s += 512) w2s[s] = W2[s];
    int R0 = blockIdx.x * 32;
    agg_core(y1, maskb, dinv, b1, redbuf, mlds, hbuf, R0);
    // y2 = dinv * (h1 @ W2), written straight into fragment order (all 512 thr).
    {
        int nn = tid & 15, q = (tid >> 4) & 3, ct = (tid >> 6) & 3, half = tid >> 8;
        int col = ct * 16 + nn;
        float dot[4] = {0, 0, 0, 0};
        for (int m = 0; m < 64; ++m) {
            float wv = w2s[m * 64 + col];
#pragma unroll
            for (int t = 0; t < 4; ++t)
                dot[t] = fmaf(hbuf[(q * 8 + half * 4 + t) * 66 + m], wv, dot[t]);
        }
        unsigned short v[4];
#pragma unroll
        for (int t = 0; t < 4; ++t) v[t] = f2bf(dinv[R0 + q * 8 + half * 4 + t] * dot[t]);
        uint2 u;
        u.x = (unsigned)v[0] | ((unsigned)v[1] << 16);
        u.y = (unsigned)v[2] | ((unsigned)v[3] << 16);
        int fragidx = (blockIdx.x * 4 + ct) * 64 + q * 16 + nn;
        ((uint2*)y2)[fragidx * 2 + half] = u;
    }
}

// ---------- kernel 3: layer 2 agg + h2 + scalar head (fused) ----------
__global__ __launch_bounds__(512) void k_layer2(const uint4* __restrict__ y2,
                                                const unsigned int* __restrict__ maskb,
                                                const float* __restrict__ dinv,
                                                const float* __restrict__ b2,
                                                const float* __restrict__ cw,
                                                const float* __restrict__ cb,
                                                float* __restrict__ out) {
    __shared__ float redbuf[8 * 2048];             // 64 KB
    __shared__ unsigned int mlds[32 * MSTRIDE];    // 32.5 KB
    __shared__ float hbuf[32 * 66];                // 8.25 KB
    __shared__ float cws[64];
    int tid = threadIdx.x;
    if (tid < 64) cws[tid] = cw[tid];
    int R0 = blockIdx.x * 32;
    agg_core(y2, maskb, dinv, b2, redbuf, mlds, hbuf, R0);
    // out[i] = h2[i,:] . cw + cb ; 512 threads = 32 rows x 16 groups of 4 cols
    int row = tid >> 4, cg = tid & 15;
    float v = 0.0f;
#pragma unroll
    for (int e = 0; e < 4; ++e) {
        int c = cg * 4 + e;
        v = fmaf(hbuf[row * 66 + c], cws[c], v);
    }
    v += __shfl_down(v, 8);
    v += __shfl_down(v, 4);
    v += __shfl_down(v, 2);
    v += __shfl_down(v, 1);
    if (cg == 0) out[R0 + row] = v + cb[0];
}

// ---------- launch ----------
extern "C" void kernel_launch(void* const* d_in, const int* in_sizes, int n_in,
                              void* d_out, int out_size, void* d_ws, size_t ws_size,
                              hipStream_t stream) {
    const float* states = (const float*)d_in[0];
    const float* W1 = (const float*)d_in[1];
    const float* b1 = (const float*)d_in[2];
    const float* W2 = (const float*)d_in[3];
    const float* b2 = (const float*)d_in[4];
    const float* cw = (const float*)d_in[5];
    const float* cb = (const float*)d_in[6];
    float* out = (float*)d_out;
    float* mout = out + NPTS;  // mask floats follow out[8192]

    char* ws = (char*)d_ws;
    float* dinv               = (float*)(ws);                          // 64 KB
    unsigned long long* maskb = (unsigned long long*)(ws + (1 << 16)); // 8 MiB
    uint4* y1                 = (uint4*)(ws + (1 << 16) + (8 << 20));  // 1 MiB
    uint4* y2                 = (uint4*)(ws + (1 << 16) + (9 << 20));  // 1 MiB

    hipLaunchKernelGGL(k_mask,   dim3(512), dim3(256), 0, stream,
                       states, W1, mout, maskb, dinv, y1);
    hipLaunchKernelGGL(k_layer1, dim3(256), dim3(512), 0, stream,
                       y1, (const unsigned int*)maskb, dinv, b1, W2, y2);
    hipLaunchKernelGGL(k_layer2, dim3(256), dim3(512), 0, stream,
                       y2, (const unsigned int*)maskb, dinv, b2, cw, cb, out);
}